// Round 1
// baseline (1080.207 us; speedup 1.0000x reference)
//
#include <hip/hip_runtime.h>
#include <hip/hip_bf16.h>
#include <math.h>

#define T_TOK 2048
#define H_DIM 2048
#define E_EXP 16
#define I_DIM 512
#define TWO_I 1024
#define ROUTED_SCALE 1.5f
#define SWIGLU_LIMIT 7.0f

#define BM 64
#define BN 64
#define KC 32
#define PADMAX 5120      // 4096 assignments + 16*64 padding max
#define MAX_TILES 80     // PADMAX / BM

// ---------------- init: zero expert counters, mark all slots invalid ----------------
__global__ void init_kernel(int* cnt, int* A_tok) {
    int i = blockIdx.x * 256 + threadIdx.x;
    if (i < E_EXP) cnt[i] = 0;
    if (i < PADMAX) A_tok[i] = -1;
}

// ---------------- router: one wave per token ----------------
__global__ __launch_bounds__(256) void router_kernel(
    const float* __restrict__ hs, const float* __restrict__ gw,
    const float* __restrict__ bias, int* cnt, int* tok_list, float* w_list)
{
    int wave = threadIdx.x >> 6;
    int lane = threadIdx.x & 63;
    int t = blockIdx.x * 4 + wave;
    if (t >= T_TOK) return;
    const float* x = hs + (size_t)t * H_DIM;

    float acc[E_EXP];
#pragma unroll
    for (int e = 0; e < E_EXP; ++e) acc[e] = 0.f;

    for (int h = lane; h < H_DIM; h += 64) {
        float xv = x[h];
#pragma unroll
        for (int e = 0; e < E_EXP; ++e)
            acc[e] = fmaf(xv, gw[e * H_DIM + h], acc[e]);
    }
#pragma unroll
    for (int e = 0; e < E_EXP; ++e) {
        for (int m = 32; m >= 1; m >>= 1)
            acc[e] += __shfl_xor(acc[e], m, 64);
    }
    if (lane == 0) {
        float sc[E_EXP], bsc[E_EXP];
#pragma unroll
        for (int e = 0; e < E_EXP; ++e) {
            sc[e] = 1.f / (1.f + expf(-acc[e]));
            bsc[e] = sc[e] + bias[e];
        }
        // top-2 on biased scores (lowest index wins ties, like lax.top_k)
        int e0 = 0; float b0 = bsc[0];
#pragma unroll
        for (int e = 1; e < E_EXP; ++e) if (bsc[e] > b0) { b0 = bsc[e]; e0 = e; }
        int e1 = -1; float b1 = -1e30f;
#pragma unroll
        for (int e = 0; e < E_EXP; ++e) {
            if (e == e0) continue;
            if (bsc[e] > b1) { b1 = bsc[e]; e1 = e; }
        }
        float s0 = sc[e0], s1 = sc[e1];
        float inv = ROUTED_SCALE / (s0 + s1);
        float w0 = s0 * inv, w1 = s1 * inv;
        int p0 = atomicAdd(&cnt[e0], 1);
        tok_list[e0 * T_TOK + p0] = t;
        w_list[e0 * T_TOK + p0] = w0;
        int p1 = atomicAdd(&cnt[e1], 1);
        tok_list[e1 * T_TOK + p1] = t;
        w_list[e1 * T_TOK + p1] = w1;
    }
}

// ---------------- build padded offsets + tile descriptors ----------------
__global__ void build_tiles(const int* cnt, int* offs, int* tile_e, int* tile_r0, int* n_tiles)
{
    if (threadIdx.x != 0 || blockIdx.x != 0) return;
    int off = 0, nt = 0;
    for (int e = 0; e < E_EXP; ++e) {
        offs[e] = off;
        int c = cnt[e];
        int ntile = (c + BM - 1) / BM;
        for (int j = 0; j < ntile; ++j) {
            tile_e[nt] = e;
            tile_r0[nt] = off + j * BM;
            ++nt;
        }
        off += ntile * BM;
    }
    offs[E_EXP] = off;
    *n_tiles = nt;
}

// ---------------- scatter into compacted assignment array ----------------
__global__ void scatter_kernel(const int* cnt, const int* offs,
    const int* tok_list, const float* w_list, int* A_tok, float* A_w)
{
    int idx = blockIdx.x * 256 + threadIdx.x;
    if (idx >= E_EXP * T_TOK) return;
    int e = idx >> 11;          // / T_TOK
    int pos = idx & (T_TOK - 1);
    if (pos < cnt[e]) {
        int slot = offs[e] + pos;
        A_tok[slot] = tok_list[idx];
        A_w[slot] = w_list[idx];
    }
}

// ---------------- GEMM1 + SwiGLU: act[slot][I] = f(x @ w13_e^T) ----------------
__global__ __launch_bounds__(256) void gemm1_act(
    const float* __restrict__ hs, const float* __restrict__ w13,
    const int* __restrict__ A_tok,
    const int* __restrict__ tile_e, const int* __restrict__ tile_r0,
    const int* __restrict__ n_tiles, float* __restrict__ act)
{
    int tile = blockIdx.x;
    if (tile >= *n_tiles) return;
    int e = tile_e[tile];
    int row0 = tile_r0[tile];
    int i0 = blockIdx.y * BN;
    int tid = threadIdx.x;

    __shared__ float Xs[BM][KC + 1];
    __shared__ float Gs[BN][KC + 1];
    __shared__ float Us[BN][KC + 1];
    __shared__ int toks[BM];
    if (tid < BM) toks[tid] = A_tok[row0 + tid];
    __syncthreads();

    int tx = tid & 15, ty = tid >> 4;
    float accG[4][4] = {{0.f}}, accU[4][4] = {{0.f}};

    const float* wg_base = w13 + ((size_t)e * TWO_I + i0) * H_DIM;
    const float* wu_base = w13 + ((size_t)e * TWO_I + I_DIM + i0) * H_DIM;

    for (int k0 = 0; k0 < H_DIM; k0 += KC) {
#pragma unroll
        for (int l = 0; l < 8; ++l) {
            int idx = tid + l * 256;
            int r = idx >> 5, c = idx & 31;
            int tok = toks[r];
            Xs[r][c] = (tok >= 0) ? hs[(size_t)tok * H_DIM + k0 + c] : 0.f;
            Gs[r][c] = wg_base[(size_t)r * H_DIM + k0 + c];
            Us[r][c] = wu_base[(size_t)r * H_DIM + k0 + c];
        }
        __syncthreads();
#pragma unroll
        for (int k = 0; k < KC; ++k) {
            float xv[4], gv[4], uv[4];
#pragma unroll
            for (int j = 0; j < 4; ++j) {
                xv[j] = Xs[ty * 4 + j][k];
                gv[j] = Gs[tx * 4 + j][k];
                uv[j] = Us[tx * 4 + j][k];
            }
#pragma unroll
            for (int a = 0; a < 4; ++a)
#pragma unroll
                for (int b = 0; b < 4; ++b) {
                    accG[a][b] = fmaf(xv[a], gv[b], accG[a][b]);
                    accU[a][b] = fmaf(xv[a], uv[b], accU[a][b]);
                }
        }
        __syncthreads();
    }
#pragma unroll
    for (int a = 0; a < 4; ++a) {
        int r = row0 + ty * 4 + a;
#pragma unroll
        for (int b = 0; b < 4; ++b) {
            float g = fminf(accG[a][b], SWIGLU_LIMIT);
            float u = fminf(fmaxf(accU[a][b], -SWIGLU_LIMIT), SWIGLU_LIMIT);
            float s = 1.f / (1.f + expf(-g));
            act[(size_t)r * I_DIM + i0 + tx * 4 + b] = g * s * u;
        }
    }
}

// ---------------- GEMM2 + weighted scatter-add ----------------
__global__ __launch_bounds__(256) void gemm2_scatter(
    const float* __restrict__ act, const float* __restrict__ w2,
    const int* __restrict__ A_tok, const float* __restrict__ A_w,
    const int* __restrict__ tile_e, const int* __restrict__ tile_r0,
    const int* __restrict__ n_tiles, float* __restrict__ out)
{
    int tile = blockIdx.x;
    if (tile >= *n_tiles) return;
    int e = tile_e[tile];
    int row0 = tile_r0[tile];
    int h0 = blockIdx.y * BN;
    int tid = threadIdx.x;

    __shared__ float As[BM][KC + 1];
    __shared__ float Bs[BN][KC + 1];
    __shared__ int toks[BM];
    __shared__ float wts[BM];
    if (tid < BM) { toks[tid] = A_tok[row0 + tid]; wts[tid] = A_w[row0 + tid]; }
    __syncthreads();

    int tx = tid & 15, ty = tid >> 4;
    float acc[4][4] = {{0.f}};
    const float* b_base = w2 + ((size_t)e * H_DIM + h0) * I_DIM;

    for (int k0 = 0; k0 < I_DIM; k0 += KC) {
#pragma unroll
        for (int l = 0; l < 8; ++l) {
            int idx = tid + l * 256;
            int r = idx >> 5, c = idx & 31;
            As[r][c] = act[(size_t)(row0 + r) * I_DIM + k0 + c];
            Bs[r][c] = b_base[(size_t)r * I_DIM + k0 + c];
        }
        __syncthreads();
#pragma unroll
        for (int k = 0; k < KC; ++k) {
            float av[4], bv[4];
#pragma unroll
            for (int j = 0; j < 4; ++j) {
                av[j] = As[ty * 4 + j][k];
                bv[j] = Bs[tx * 4 + j][k];
            }
#pragma unroll
            for (int a = 0; a < 4; ++a)
#pragma unroll
                for (int b = 0; b < 4; ++b)
                    acc[a][b] = fmaf(av[a], bv[b], acc[a][b]);
        }
        __syncthreads();
    }
#pragma unroll
    for (int a = 0; a < 4; ++a) {
        int r = ty * 4 + a;
        int tok = toks[r];
        if (tok < 0) continue;
        float w = wts[r];
#pragma unroll
        for (int b = 0; b < 4; ++b)
            atomicAdd(&out[(size_t)tok * H_DIM + h0 + tx * 4 + b], acc[a][b] * w);
    }
}

extern "C" void kernel_launch(void* const* d_in, const int* in_sizes, int n_in,
                              void* d_out, int out_size, void* d_ws, size_t ws_size,
                              hipStream_t stream) {
    const float* hs   = (const float*)d_in[0];
    const float* gw   = (const float*)d_in[1];
    const float* bias = (const float*)d_in[2];
    const float* w13  = (const float*)d_in[3];
    const float* w2   = (const float*)d_in[4];
    float* out = (float*)d_out;

    char* ws = (char*)d_ws;
    int*   cnt      = (int*)(ws + 0);        // 16 ints
    int*   n_tiles  = (int*)(ws + 64);       // 1 int
    int*   offs     = (int*)(ws + 128);      // 17 ints
    int*   tile_e   = (int*)(ws + 256);      // 80 ints
    int*   tile_r0  = (int*)(ws + 1024);     // 80 ints
    int*   tok_list = (int*)(ws + 2048);     // 32768 ints  -> end 133120
    float* w_list   = (float*)(ws + 133120); // 32768 floats-> end 264192
    int*   A_tok    = (int*)(ws + 264192);   // 5120 ints   -> end 284672
    float* A_w      = (float*)(ws + 284672); // 5120 floats -> end 305152
    float* act      = (float*)(ws + 305152); // 5120*512 floats -> end ~10.6 MiB

    hipMemsetAsync(d_out, 0, (size_t)T_TOK * H_DIM * sizeof(float), stream);

    init_kernel<<<(PADMAX + 255) / 256, 256, 0, stream>>>(cnt, A_tok);
    router_kernel<<<T_TOK / 4, 256, 0, stream>>>(hs, gw, bias, cnt, tok_list, w_list);
    build_tiles<<<1, 64, 0, stream>>>(cnt, offs, tile_e, tile_r0, n_tiles);
    scatter_kernel<<<(E_EXP * T_TOK + 255) / 256, 256, 0, stream>>>(cnt, offs, tok_list, w_list, A_tok, A_w);

    dim3 g1(MAX_TILES, I_DIM / BN);   // (80, 8)
    gemm1_act<<<g1, 256, 0, stream>>>(hs, w13, A_tok, tile_e, tile_r0, n_tiles, act);

    dim3 g2(MAX_TILES, H_DIM / BN);   // (80, 32)
    gemm2_scatter<<<g2, 256, 0, stream>>>(act, w2, A_tok, A_w, tile_e, tile_r0, n_tiles, out);
}

// Round 2
// 379.187 us; speedup vs baseline: 2.8487x; 2.8487x over previous
//
#include <hip/hip_runtime.h>
#include <hip/hip_bf16.h>
#include <math.h>

#define T_TOK 2048
#define H_DIM 2048
#define E_EXP 16
#define I_DIM 512
#define TWO_I 1024
#define ROUTED_SCALE 1.5f
#define SWIGLU_LIMIT 7.0f

#define BM 64
#define BN 64
#define PADMAX 5120      // 4096 assignments + 16*64 padding max
#define MAX_TILES 80     // PADMAX / BM
#define LDK 40           // LDS row stride in bf16 (32 + 8 pad -> 2-way max conflict)

typedef __attribute__((ext_vector_type(8))) short bf16x8;
typedef __attribute__((ext_vector_type(4))) float f32x4;

__device__ inline unsigned short f2bf(float f) {
    unsigned int u = __builtin_bit_cast(unsigned int, f);
    return (unsigned short)((u + 0x7FFFu + ((u >> 16) & 1u)) >> 16);
}
__device__ inline bf16x8 pack8(float4 a, float4 b) {
    bf16x8 v;
    v[0] = (short)f2bf(a.x); v[1] = (short)f2bf(a.y);
    v[2] = (short)f2bf(a.z); v[3] = (short)f2bf(a.w);
    v[4] = (short)f2bf(b.x); v[5] = (short)f2bf(b.y);
    v[6] = (short)f2bf(b.z); v[7] = (short)f2bf(b.w);
    return v;
}

// ---------------- init ----------------
__global__ void init_kernel(int* cnt, int* A_tok) {
    int i = blockIdx.x * 256 + threadIdx.x;
    if (i < E_EXP) cnt[i] = 0;
    if (i < PADMAX) A_tok[i] = -1;
}

// ---------------- router: one wave per token (fp32, matches reference gate) ----------------
__global__ __launch_bounds__(256) void router_kernel(
    const float* __restrict__ hs, const float* __restrict__ gw,
    const float* __restrict__ bias, int* cnt, int* tok_list, float* w_list)
{
    int wave = threadIdx.x >> 6;
    int lane = threadIdx.x & 63;
    int t = blockIdx.x * 4 + wave;
    if (t >= T_TOK) return;
    const float* x = hs + (size_t)t * H_DIM;

    float acc[E_EXP];
#pragma unroll
    for (int e = 0; e < E_EXP; ++e) acc[e] = 0.f;

    for (int h = lane; h < H_DIM; h += 64) {
        float xv = x[h];
#pragma unroll
        for (int e = 0; e < E_EXP; ++e)
            acc[e] = fmaf(xv, gw[e * H_DIM + h], acc[e]);
    }
#pragma unroll
    for (int e = 0; e < E_EXP; ++e) {
        for (int m = 32; m >= 1; m >>= 1)
            acc[e] += __shfl_xor(acc[e], m, 64);
    }
    if (lane == 0) {
        float sc[E_EXP], bsc[E_EXP];
#pragma unroll
        for (int e = 0; e < E_EXP; ++e) {
            sc[e] = 1.f / (1.f + expf(-acc[e]));
            bsc[e] = sc[e] + bias[e];
        }
        int e0 = 0; float b0 = bsc[0];
#pragma unroll
        for (int e = 1; e < E_EXP; ++e) if (bsc[e] > b0) { b0 = bsc[e]; e0 = e; }
        int e1 = -1; float b1 = -1e30f;
#pragma unroll
        for (int e = 0; e < E_EXP; ++e) {
            if (e == e0) continue;
            if (bsc[e] > b1) { b1 = bsc[e]; e1 = e; }
        }
        float s0 = sc[e0], s1 = sc[e1];
        float inv = ROUTED_SCALE / (s0 + s1);
        int p0 = atomicAdd(&cnt[e0], 1);
        tok_list[e0 * T_TOK + p0] = t;
        w_list[e0 * T_TOK + p0] = s0 * inv;
        int p1 = atomicAdd(&cnt[e1], 1);
        tok_list[e1 * T_TOK + p1] = t;
        w_list[e1 * T_TOK + p1] = s1 * inv;
    }
}

// ---------------- build padded offsets + tile descriptors ----------------
__global__ void build_tiles(const int* cnt, int* offs, int* tile_e, int* tile_r0, int* n_tiles)
{
    if (threadIdx.x != 0 || blockIdx.x != 0) return;
    int off = 0, nt = 0;
    for (int e = 0; e < E_EXP; ++e) {
        offs[e] = off;
        int c = cnt[e];
        int ntile = (c + BM - 1) / BM;
        for (int j = 0; j < ntile; ++j) {
            tile_e[nt] = e;
            tile_r0[nt] = off + j * BM;
            ++nt;
        }
        off += ntile * BM;
    }
    offs[E_EXP] = off;
    *n_tiles = nt;
}

// ---------------- scatter into compacted assignment array ----------------
__global__ void scatter_kernel(const int* cnt, const int* offs,
    const int* tok_list, const float* w_list, int* A_tok, float* A_w)
{
    int idx = blockIdx.x * 256 + threadIdx.x;
    if (idx >= E_EXP * T_TOK) return;
    int e = idx >> 11;
    int pos = idx & (T_TOK - 1);
    if (pos < cnt[e]) {
        int slot = offs[e] + pos;
        A_tok[slot] = tok_list[idx];
        A_w[slot] = w_list[idx];
    }
}

// ---------------- GEMM1 (bf16 MFMA) + SwiGLU -> act (bf16) ----------------
__global__ __launch_bounds__(256) void gemm1_act(
    const float* __restrict__ hs, const float* __restrict__ w13,
    const int* __restrict__ A_tok,
    const int* __restrict__ tile_e, const int* __restrict__ tile_r0,
    const int* __restrict__ n_tiles, unsigned short* __restrict__ act)
{
    int tile = blockIdx.x;
    if (tile >= *n_tiles) return;
    int e = tile_e[tile], row0 = tile_r0[tile];
    int i0 = blockIdx.y * BN;
    int tid = threadIdx.x;

    __shared__ short Xs[2][BM][LDK];
    __shared__ short Gs[2][BN][LDK];
    __shared__ short Us[2][BN][LDK];
    __shared__ int toks[BM];
    if (tid < BM) toks[tid] = A_tok[row0 + tid];
    __syncthreads();

    // staging assignment: thread covers row r, k-chunk of 8
    const int r  = tid >> 2;          // 0..63
    const int kc = (tid & 3) << 3;    // 0,8,16,24
    const int tokr = toks[r];
    const bool xok = tokr >= 0;
    const float* xrow = hs + (size_t)(xok ? tokr : 0) * H_DIM + kc;
    const float* grow = w13 + ((size_t)e * TWO_I + i0 + r) * H_DIM + kc;
    const float* urow = grow + (size_t)I_DIM * H_DIM;

    float4 xa, xb, ga, gb, ua, ub;
    const float4 fz = make_float4(0.f, 0.f, 0.f, 0.f);
#define LOADT(t) do { int k0 = (t) << 5; \
        xa = xok ? *(const float4*)(xrow + k0)     : fz; \
        xb = xok ? *(const float4*)(xrow + k0 + 4) : fz; \
        ga = *(const float4*)(grow + k0); gb = *(const float4*)(grow + k0 + 4); \
        ua = *(const float4*)(urow + k0); ub = *(const float4*)(urow + k0 + 4); } while (0)
#define WRITET(b) do { \
        *(bf16x8*)&Xs[b][r][kc] = pack8(xa, xb); \
        *(bf16x8*)&Gs[b][r][kc] = pack8(ga, gb); \
        *(bf16x8*)&Us[b][r][kc] = pack8(ua, ub); } while (0)

    const int l  = tid & 63;
    const int w  = tid >> 6;
    const int wm = w >> 1, wn = w & 1;     // wave quadrant: 32x32
    const int lr = l & 15;
    const int lk = (l >> 4) << 3;          // 0,8,16,24

    f32x4 zero = {0.f, 0.f, 0.f, 0.f};
    f32x4 aG[2][2], aU[2][2];
#pragma unroll
    for (int m = 0; m < 2; ++m)
#pragma unroll
        for (int n = 0; n < 2; ++n) { aG[m][n] = zero; aU[m][n] = zero; }

    LOADT(0);
    WRITET(0);
    __syncthreads();
    int cur = 0;
    const int NT = H_DIM / 32;   // 64
    for (int t = 0; t < NT; ++t) {
        const bool more = (t + 1 < NT);
        if (more) LOADT(t + 1);

        bf16x8 a0 = *(const bf16x8*)&Xs[cur][wm * 32 + lr][lk];
        bf16x8 a1 = *(const bf16x8*)&Xs[cur][wm * 32 + 16 + lr][lk];
        bf16x8 g0 = *(const bf16x8*)&Gs[cur][wn * 32 + lr][lk];
        bf16x8 g1 = *(const bf16x8*)&Gs[cur][wn * 32 + 16 + lr][lk];
        bf16x8 u0 = *(const bf16x8*)&Us[cur][wn * 32 + lr][lk];
        bf16x8 u1 = *(const bf16x8*)&Us[cur][wn * 32 + 16 + lr][lk];

        aG[0][0] = __builtin_amdgcn_mfma_f32_16x16x32_bf16(a0, g0, aG[0][0], 0, 0, 0);
        aG[0][1] = __builtin_amdgcn_mfma_f32_16x16x32_bf16(a0, g1, aG[0][1], 0, 0, 0);
        aG[1][0] = __builtin_amdgcn_mfma_f32_16x16x32_bf16(a1, g0, aG[1][0], 0, 0, 0);
        aG[1][1] = __builtin_amdgcn_mfma_f32_16x16x32_bf16(a1, g1, aG[1][1], 0, 0, 0);
        aU[0][0] = __builtin_amdgcn_mfma_f32_16x16x32_bf16(a0, u0, aU[0][0], 0, 0, 0);
        aU[0][1] = __builtin_amdgcn_mfma_f32_16x16x32_bf16(a0, u1, aU[0][1], 0, 0, 0);
        aU[1][0] = __builtin_amdgcn_mfma_f32_16x16x32_bf16(a1, u0, aU[1][0], 0, 0, 0);
        aU[1][1] = __builtin_amdgcn_mfma_f32_16x16x32_bf16(a1, u1, aU[1][1], 0, 0, 0);

        if (more) WRITET(cur ^ 1);
        __syncthreads();
        cur ^= 1;
    }
#undef LOADT
#undef WRITET

    // epilogue: clamp + silu(gate) * up, write bf16 act
#pragma unroll
    for (int m = 0; m < 2; ++m)
#pragma unroll
        for (int n = 0; n < 2; ++n) {
            int col = i0 + wn * 32 + n * 16 + lr;
            int rbase = row0 + wm * 32 + m * 16 + ((l >> 4) << 2);
#pragma unroll
            for (int q = 0; q < 4; ++q) {
                float g = fminf(aG[m][n][q], SWIGLU_LIMIT);
                float u = fminf(fmaxf(aU[m][n][q], -SWIGLU_LIMIT), SWIGLU_LIMIT);
                float s = 1.f / (1.f + __expf(-g));
                act[(size_t)(rbase + q) * I_DIM + col] = f2bf(g * s * u);
            }
        }
}

// ---------------- GEMM2 (bf16 MFMA) + weighted scatter-add ----------------
__global__ __launch_bounds__(256) void gemm2_scatter(
    const unsigned short* __restrict__ act, const float* __restrict__ w2,
    const int* __restrict__ A_tok, const float* __restrict__ A_w,
    const int* __restrict__ tile_e, const int* __restrict__ tile_r0,
    const int* __restrict__ n_tiles, float* __restrict__ out)
{
    int tile = blockIdx.x;
    if (tile >= *n_tiles) return;
    int e = tile_e[tile], row0 = tile_r0[tile];
    int h0 = blockIdx.y * BN;
    int tid = threadIdx.x;

    __shared__ short As[2][BM][LDK];
    __shared__ short Bs[2][BN][LDK];
    __shared__ int toks[BM];
    __shared__ float wts[BM];
    if (tid < BM) { toks[tid] = A_tok[row0 + tid]; wts[tid] = A_w[row0 + tid]; }
    __syncthreads();

    const int r  = tid >> 2;
    const int kc = (tid & 3) << 3;
    const unsigned short* arow = act + (size_t)(row0 + r) * I_DIM + kc;
    const float* brow = w2 + ((size_t)e * H_DIM + h0 + r) * I_DIM + kc;

    bf16x8 av; float4 ba, bb;
#define LOADT(t) do { int k0 = (t) << 5; \
        av = *(const bf16x8*)(arow + k0); \
        ba = *(const float4*)(brow + k0); bb = *(const float4*)(brow + k0 + 4); } while (0)
#define WRITET(b) do { \
        *(bf16x8*)&As[b][r][kc] = av; \
        *(bf16x8*)&Bs[b][r][kc] = pack8(ba, bb); } while (0)

    const int l  = tid & 63;
    const int w  = tid >> 6;
    const int wm = w >> 1, wn = w & 1;
    const int lr = l & 15;
    const int lk = (l >> 4) << 3;

    f32x4 zero = {0.f, 0.f, 0.f, 0.f};
    f32x4 acc[2][2];
#pragma unroll
    for (int m = 0; m < 2; ++m)
#pragma unroll
        for (int n = 0; n < 2; ++n) acc[m][n] = zero;

    LOADT(0);
    WRITET(0);
    __syncthreads();
    int cur = 0;
    const int NT = I_DIM / 32;   // 16
    for (int t = 0; t < NT; ++t) {
        const bool more = (t + 1 < NT);
        if (more) LOADT(t + 1);

        bf16x8 a0 = *(const bf16x8*)&As[cur][wm * 32 + lr][lk];
        bf16x8 a1 = *(const bf16x8*)&As[cur][wm * 32 + 16 + lr][lk];
        bf16x8 b0 = *(const bf16x8*)&Bs[cur][wn * 32 + lr][lk];
        bf16x8 b1 = *(const bf16x8*)&Bs[cur][wn * 32 + 16 + lr][lk];

        acc[0][0] = __builtin_amdgcn_mfma_f32_16x16x32_bf16(a0, b0, acc[0][0], 0, 0, 0);
        acc[0][1] = __builtin_amdgcn_mfma_f32_16x16x32_bf16(a0, b1, acc[0][1], 0, 0, 0);
        acc[1][0] = __builtin_amdgcn_mfma_f32_16x16x32_bf16(a1, b0, acc[1][0], 0, 0, 0);
        acc[1][1] = __builtin_amdgcn_mfma_f32_16x16x32_bf16(a1, b1, acc[1][1], 0, 0, 0);

        if (more) WRITET(cur ^ 1);
        __syncthreads();
        cur ^= 1;
    }
#undef LOADT
#undef WRITET

#pragma unroll
    for (int m = 0; m < 2; ++m)
#pragma unroll
        for (int n = 0; n < 2; ++n) {
            int col = h0 + wn * 32 + n * 16 + lr;
            int rbase = wm * 32 + m * 16 + ((l >> 4) << 2);
#pragma unroll
            for (int q = 0; q < 4; ++q) {
                int slot = rbase + q;
                int tok = toks[slot];
                if (tok >= 0)
                    atomicAdd(&out[(size_t)tok * H_DIM + col], acc[m][n][q] * wts[slot]);
            }
        }
}

extern "C" void kernel_launch(void* const* d_in, const int* in_sizes, int n_in,
                              void* d_out, int out_size, void* d_ws, size_t ws_size,
                              hipStream_t stream) {
    const float* hs   = (const float*)d_in[0];
    const float* gw   = (const float*)d_in[1];
    const float* bias = (const float*)d_in[2];
    const float* w13  = (const float*)d_in[3];
    const float* w2   = (const float*)d_in[4];
    float* out = (float*)d_out;

    char* ws = (char*)d_ws;
    int*   cnt      = (int*)(ws + 0);        // 16 ints
    int*   n_tiles  = (int*)(ws + 64);       // 1 int
    int*   offs     = (int*)(ws + 128);      // 17 ints
    int*   tile_e   = (int*)(ws + 256);      // 80 ints
    int*   tile_r0  = (int*)(ws + 1024);     // 80 ints
    int*   tok_list = (int*)(ws + 2048);     // 32768 ints  -> 133120
    float* w_list   = (float*)(ws + 133120); // 32768 floats-> 264192
    int*   A_tok    = (int*)(ws + 264192);   // 5120 ints   -> 284672
    float* A_w      = (float*)(ws + 284672); // 5120 floats -> 305152
    unsigned short* act = (unsigned short*)(ws + 305152); // 5120*512 bf16 -> ~5.5 MB

    hipMemsetAsync(d_out, 0, (size_t)T_TOK * H_DIM * sizeof(float), stream);

    init_kernel<<<(PADMAX + 255) / 256, 256, 0, stream>>>(cnt, A_tok);
    router_kernel<<<T_TOK / 4, 256, 0, stream>>>(hs, gw, bias, cnt, tok_list, w_list);
    build_tiles<<<1, 64, 0, stream>>>(cnt, offs, tile_e, tile_r0, n_tiles);
    scatter_kernel<<<(E_EXP * T_TOK + 255) / 256, 256, 0, stream>>>(cnt, offs, tok_list, w_list, A_tok, A_w);

    dim3 g1(MAX_TILES, I_DIM / BN);   // (80, 8)
    gemm1_act<<<g1, 256, 0, stream>>>(hs, w13, A_tok, tile_e, tile_r0, n_tiles, act);

    dim3 g2(MAX_TILES, H_DIM / BN);   // (80, 32)
    gemm2_scatter<<<g2, 256, 0, stream>>>(act, w2, A_tok, A_w, tile_e, tile_r0, n_tiles, out);
}

// Round 3
// 196.454 us; speedup vs baseline: 5.4985x; 1.9302x over previous
//
#include <hip/hip_runtime.h>
#include <hip/hip_bf16.h>
#include <math.h>

#define T_TOK 2048
#define H_DIM 2048
#define E_EXP 16
#define I_DIM 512
#define TWO_I 1024
#define ROUTED_SCALE 1.5f
#define SWIGLU_LIMIT 7.0f

#define BM 64
#define KC 64
#define PADMAX 5120
#define MAX_TILES 80

typedef __attribute__((ext_vector_type(8))) short bf16x8;
typedef __attribute__((ext_vector_type(4))) float f32x4;
typedef unsigned short u16;

__device__ inline u16 f2bf(float f) {
    return __builtin_bit_cast(u16, __float2bfloat16(f));
}
__device__ inline bf16x8 pack8(float4 a, float4 b) {
    bf16x8 v;
    v[0] = (short)f2bf(a.x); v[1] = (short)f2bf(a.y);
    v[2] = (short)f2bf(a.z); v[3] = (short)f2bf(a.w);
    v[4] = (short)f2bf(b.x); v[5] = (short)f2bf(b.y);
    v[6] = (short)f2bf(b.z); v[7] = (short)f2bf(b.w);
    return v;
}

// swizzled ushort index for 64-elem bf16 rows: logical (row, k) -> row*64 + (k ^ ((row&7)<<3))
#define SWZ(row, k) ((row) * 64 + ((k) ^ (((row) & 7) << 3)))

// ---------------- router: one wave per token; also emits hs in bf16 ----------------
__global__ __launch_bounds__(256) void router_kernel(
    const float* __restrict__ hs, const float* __restrict__ gw,
    const float* __restrict__ bias, int* cnt, int* tok_list, float* w_list,
    u16* __restrict__ hs_bf)
{
    int wave = threadIdx.x >> 6;
    int lane = threadIdx.x & 63;
    int t = blockIdx.x * 4 + wave;
    if (t >= T_TOK) return;
    const float* x = hs + (size_t)t * H_DIM;

    float acc[E_EXP];
#pragma unroll
    for (int e = 0; e < E_EXP; ++e) acc[e] = 0.f;

#pragma unroll 2
    for (int c = 0; c < 8; ++c) {
        int col = c * 256 + lane * 4;
        float4 xv = *(const float4*)(x + col);
        ushort4 pv;
        pv.x = f2bf(xv.x); pv.y = f2bf(xv.y); pv.z = f2bf(xv.z); pv.w = f2bf(xv.w);
        *(ushort4*)(hs_bf + (size_t)t * H_DIM + col) = pv;
#pragma unroll
        for (int e = 0; e < E_EXP; ++e) {
            float4 gv = *(const float4*)(gw + (size_t)e * H_DIM + col);
            acc[e] = fmaf(xv.x, gv.x, acc[e]);
            acc[e] = fmaf(xv.y, gv.y, acc[e]);
            acc[e] = fmaf(xv.z, gv.z, acc[e]);
            acc[e] = fmaf(xv.w, gv.w, acc[e]);
        }
    }
#pragma unroll
    for (int e = 0; e < E_EXP; ++e) {
        for (int m = 32; m >= 1; m >>= 1)
            acc[e] += __shfl_xor(acc[e], m, 64);
    }
    if (lane == 0) {
        float sc[E_EXP], bsc[E_EXP];
#pragma unroll
        for (int e = 0; e < E_EXP; ++e) {
            sc[e] = 1.f / (1.f + expf(-acc[e]));
            bsc[e] = sc[e] + bias[e];
        }
        int e0 = 0; float b0 = bsc[0];
#pragma unroll
        for (int e = 1; e < E_EXP; ++e) if (bsc[e] > b0) { b0 = bsc[e]; e0 = e; }
        int e1 = -1; float b1 = -1e30f;
#pragma unroll
        for (int e = 0; e < E_EXP; ++e) {
            if (e == e0) continue;
            if (bsc[e] > b1) { b1 = bsc[e]; e1 = e; }
        }
        float s0 = sc[e0], s1 = sc[e1];
        float inv = ROUTED_SCALE / (s0 + s1);
        int p0 = atomicAdd(&cnt[e0], 1);
        tok_list[e0 * T_TOK + p0] = t;
        w_list[e0 * T_TOK + p0] = s0 * inv;
        int p1 = atomicAdd(&cnt[e1], 1);
        tok_list[e1 * T_TOK + p1] = t;
        w_list[e1 * T_TOK + p1] = s1 * inv;
    }
}

// ---------------- fused: compact assignments (with -1 padding) + tile descriptors ----------------
__global__ void scatter_build(const int* __restrict__ cnt,
    const int* __restrict__ tok_list, const float* __restrict__ w_list,
    int* A_tok, float* A_w, int* tile_e, int* tile_r0)
{
    int c[E_EXP], offs[E_EXP + 1];
    offs[0] = 0;
#pragma unroll
    for (int e = 0; e < E_EXP; ++e) {
        c[e] = cnt[e];
        offs[e + 1] = offs[e] + ((c[e] + BM - 1) & ~(BM - 1));
    }
    int idx = blockIdx.x * 256 + threadIdx.x;
    int e = idx >> 11;
    int pos = idx & (T_TOK - 1);
    int ce = c[e];
    int pe = (ce + BM - 1) & ~(BM - 1);
    if (pos < ce) {
        A_tok[offs[e] + pos] = tok_list[idx];
        A_w[offs[e] + pos] = w_list[idx];
    } else if (pos < pe) {
        A_tok[offs[e] + pos] = -1;
        A_w[offs[e] + pos] = 0.f;
    }
    if (idx == 0) {
        int nt = 0;
        for (int ee = 0; ee < E_EXP; ++ee) {
            int ntile = (c[ee] + BM - 1) >> 6;
            for (int j = 0; j < ntile; ++j) {
                tile_e[nt] = ee;
                tile_r0[nt] = offs[ee] + j * BM;
                ++nt;
            }
        }
        for (; nt < MAX_TILES; ++nt) tile_e[nt] = -1;
    }
}

// ---------------- GEMM1 (bf16 MFMA, KC=64, swizzled LDS) + SwiGLU -> act bf16 ----------------
__global__ __launch_bounds__(256, 3) void gemm1_act(
    const u16* __restrict__ hs_bf, const float* __restrict__ w13,
    const int* __restrict__ A_tok,
    const int* __restrict__ tile_e, const int* __restrict__ tile_r0,
    u16* __restrict__ act)
{
    // XCD-chunked bijective swizzle: nwg=640, 80 per XCD -> XCD x owns y-stripe x
    int b = blockIdx.x;
    int id = (b & 7) * 80 + (b >> 3);
    int tile = id % MAX_TILES;
    int y = id / MAX_TILES;              // 0..7
    int e = tile_e[tile];
    if (e < 0) return;
    int row0 = tile_r0[tile];
    int i0 = y * 64;
    int tid = threadIdx.x;

    __shared__ u16 Xs[2][4096];
    __shared__ u16 Gs[2][4096];
    __shared__ u16 Us[2][4096];

    // staging role: row r (0..63), 16-elem quarter kq
    const int r  = tid >> 2;
    const int kq = tid & 3;
    const int tok_r = A_tok[row0 + r];
    const bool xok = tok_r >= 0;
    const u16* xsrc = hs_bf + (size_t)(xok ? tok_r : 0) * H_DIM + kq * 16;
    const float* gsrc = w13 + ((size_t)e * TWO_I + i0 + r) * H_DIM + kq * 16;
    const float* usrc = gsrc + (size_t)I_DIM * H_DIM;
    const int wb0 = SWZ(r, kq * 16);
    const int wb1 = SWZ(r, kq * 16 + 8);
    const bf16x8 BZ = {0, 0, 0, 0, 0, 0, 0, 0};

    bf16x8 xv0, xv1;
    float4 gv0, gv1, gv2, gv3, uv0, uv1, uv2, uv3;

#define G1_LOAD(t) do { int k0 = (t) * KC; \
    xv0 = xok ? *(const bf16x8*)(xsrc + k0)     : BZ; \
    xv1 = xok ? *(const bf16x8*)(xsrc + k0 + 8) : BZ; \
    gv0 = *(const float4*)(gsrc + k0);      gv1 = *(const float4*)(gsrc + k0 + 4); \
    gv2 = *(const float4*)(gsrc + k0 + 8);  gv3 = *(const float4*)(gsrc + k0 + 12); \
    uv0 = *(const float4*)(usrc + k0);      uv1 = *(const float4*)(usrc + k0 + 4); \
    uv2 = *(const float4*)(usrc + k0 + 8);  uv3 = *(const float4*)(usrc + k0 + 12); } while (0)

#define G1_WRITE(bb) do { \
    *(bf16x8*)&Xs[bb][wb0] = xv0;             *(bf16x8*)&Xs[bb][wb1] = xv1; \
    *(bf16x8*)&Gs[bb][wb0] = pack8(gv0, gv1); *(bf16x8*)&Gs[bb][wb1] = pack8(gv2, gv3); \
    *(bf16x8*)&Us[bb][wb0] = pack8(uv0, uv1); *(bf16x8*)&Us[bb][wb1] = pack8(uv2, uv3); } while (0)

    // MFMA roles: 4 waves as 2x2 over (token32, i32)
    const int l  = tid & 63;
    const int w  = tid >> 6;
    const int wm = w >> 1, wn = w & 1;
    const int lr = l & 15;
    const int lg = l >> 4;               // 0..3
    const int ra0 = wm * 32 + lr, ra1 = ra0 + 16;
    const int rb0 = wn * 32 + lr, rb1 = rb0 + 16;
    int ia0[2], ia1[2], ib0[2], ib1[2];
#pragma unroll
    for (int kh = 0; kh < 2; ++kh) {
        int e2 = kh * 32 + lg * 8;
        ia0[kh] = SWZ(ra0, e2); ia1[kh] = SWZ(ra1, e2);
        ib0[kh] = SWZ(rb0, e2); ib1[kh] = SWZ(rb1, e2);
    }

    const f32x4 Z4 = {0.f, 0.f, 0.f, 0.f};
    f32x4 aG[2][2], aU[2][2];
#pragma unroll
    for (int m = 0; m < 2; ++m)
#pragma unroll
        for (int n = 0; n < 2; ++n) { aG[m][n] = Z4; aU[m][n] = Z4; }

    G1_LOAD(0);
    G1_WRITE(0);
    __syncthreads();
    int cur = 0;
    const int NT = H_DIM / KC;           // 32
    for (int t = 0; t < NT; ++t) {
        int tn = (t + 1 < NT) ? t + 1 : t;
        G1_LOAD(tn);
#pragma unroll
        for (int kh = 0; kh < 2; ++kh) {
            bf16x8 a0 = *(const bf16x8*)&Xs[cur][ia0[kh]];
            bf16x8 a1 = *(const bf16x8*)&Xs[cur][ia1[kh]];
            bf16x8 g0 = *(const bf16x8*)&Gs[cur][ib0[kh]];
            bf16x8 g1 = *(const bf16x8*)&Gs[cur][ib1[kh]];
            bf16x8 u0 = *(const bf16x8*)&Us[cur][ib0[kh]];
            bf16x8 u1 = *(const bf16x8*)&Us[cur][ib1[kh]];
            aG[0][0] = __builtin_amdgcn_mfma_f32_16x16x32_bf16(a0, g0, aG[0][0], 0, 0, 0);
            aG[0][1] = __builtin_amdgcn_mfma_f32_16x16x32_bf16(a0, g1, aG[0][1], 0, 0, 0);
            aG[1][0] = __builtin_amdgcn_mfma_f32_16x16x32_bf16(a1, g0, aG[1][0], 0, 0, 0);
            aG[1][1] = __builtin_amdgcn_mfma_f32_16x16x32_bf16(a1, g1, aG[1][1], 0, 0, 0);
            aU[0][0] = __builtin_amdgcn_mfma_f32_16x16x32_bf16(a0, u0, aU[0][0], 0, 0, 0);
            aU[0][1] = __builtin_amdgcn_mfma_f32_16x16x32_bf16(a0, u1, aU[0][1], 0, 0, 0);
            aU[1][0] = __builtin_amdgcn_mfma_f32_16x16x32_bf16(a1, u0, aU[1][0], 0, 0, 0);
            aU[1][1] = __builtin_amdgcn_mfma_f32_16x16x32_bf16(a1, u1, aU[1][1], 0, 0, 0);
        }
        G1_WRITE(cur ^ 1);
        __syncthreads();
        cur ^= 1;
    }
#undef G1_LOAD
#undef G1_WRITE

#pragma unroll
    for (int m = 0; m < 2; ++m)
#pragma unroll
        for (int n = 0; n < 2; ++n) {
            int col = i0 + wn * 32 + n * 16 + lr;
            int rbase = row0 + wm * 32 + m * 16 + lg * 4;
#pragma unroll
            for (int q = 0; q < 4; ++q) {
                float g = fminf(aG[m][n][q], SWIGLU_LIMIT);
                float u = fminf(fmaxf(aU[m][n][q], -SWIGLU_LIMIT), SWIGLU_LIMIT);
                float s = 1.f / (1.f + __expf(-g));
                act[(size_t)(rbase + q) * I_DIM + col] = f2bf(g * s * u);
            }
        }
}

// ---------------- GEMM2 (bf16 MFMA, KC=64, swizzled LDS) + weighted scatter-add ----------------
__global__ __launch_bounds__(256, 4) void gemm2_scatter(
    const u16* __restrict__ act, const float* __restrict__ w2,
    const int* __restrict__ A_tok, const float* __restrict__ A_w,
    const int* __restrict__ tile_e, const int* __restrict__ tile_r0,
    float* __restrict__ out)
{
    // nwg=2560, 320 per XCD -> XCD x owns y in [4x, 4x+4)
    int b = blockIdx.x;
    int id = (b & 7) * 320 + (b >> 3);
    int tile = id % MAX_TILES;
    int y = id / MAX_TILES;              // 0..31
    int e = tile_e[tile];
    if (e < 0) return;
    int row0 = tile_r0[tile];
    int h0 = y * 64;
    int tid = threadIdx.x;

    __shared__ u16 As[2][4096];
    __shared__ u16 Bs[2][4096];
    __shared__ int toks[BM];
    __shared__ float wts[BM];
    if (tid < BM) { toks[tid] = A_tok[row0 + tid]; wts[tid] = A_w[row0 + tid]; }

    const int r  = tid >> 2;
    const int kq = tid & 3;
    const u16* asrc = act + (size_t)(row0 + r) * I_DIM + kq * 16;
    const float* bsrc = w2 + ((size_t)e * H_DIM + h0 + r) * I_DIM + kq * 16;
    const int wb0 = SWZ(r, kq * 16);
    const int wb1 = SWZ(r, kq * 16 + 8);

    bf16x8 av0, av1;
    float4 bv0, bv1, bv2, bv3;

#define G2_LOAD(t) do { int k0 = (t) * KC; \
    av0 = *(const bf16x8*)(asrc + k0); av1 = *(const bf16x8*)(asrc + k0 + 8); \
    bv0 = *(const float4*)(bsrc + k0);      bv1 = *(const float4*)(bsrc + k0 + 4); \
    bv2 = *(const float4*)(bsrc + k0 + 8);  bv3 = *(const float4*)(bsrc + k0 + 12); } while (0)

#define G2_WRITE(bb) do { \
    *(bf16x8*)&As[bb][wb0] = av0;             *(bf16x8*)&As[bb][wb1] = av1; \
    *(bf16x8*)&Bs[bb][wb0] = pack8(bv0, bv1); *(bf16x8*)&Bs[bb][wb1] = pack8(bv2, bv3); } while (0)

    const int l  = tid & 63;
    const int w  = tid >> 6;
    const int wm = w >> 1, wn = w & 1;
    const int lr = l & 15;
    const int lg = l >> 4;
    const int ra0 = wm * 32 + lr, ra1 = ra0 + 16;
    const int rb0 = wn * 32 + lr, rb1 = rb0 + 16;
    int ia0[2], ia1[2], ib0[2], ib1[2];
#pragma unroll
    for (int kh = 0; kh < 2; ++kh) {
        int e2 = kh * 32 + lg * 8;
        ia0[kh] = SWZ(ra0, e2); ia1[kh] = SWZ(ra1, e2);
        ib0[kh] = SWZ(rb0, e2); ib1[kh] = SWZ(rb1, e2);
    }

    const f32x4 Z4 = {0.f, 0.f, 0.f, 0.f};
    f32x4 acc[2][2];
#pragma unroll
    for (int m = 0; m < 2; ++m)
#pragma unroll
        for (int n = 0; n < 2; ++n) acc[m][n] = Z4;

    G2_LOAD(0);
    G2_WRITE(0);
    __syncthreads();
    int cur = 0;
    const int NT = I_DIM / KC;           // 8
    for (int t = 0; t < NT; ++t) {
        int tn = (t + 1 < NT) ? t + 1 : t;
        G2_LOAD(tn);
#pragma unroll
        for (int kh = 0; kh < 2; ++kh) {
            bf16x8 a0 = *(const bf16x8*)&As[cur][ia0[kh]];
            bf16x8 a1 = *(const bf16x8*)&As[cur][ia1[kh]];
            bf16x8 b0 = *(const bf16x8*)&Bs[cur][ib0[kh]];
            bf16x8 b1 = *(const bf16x8*)&Bs[cur][ib1[kh]];
            acc[0][0] = __builtin_amdgcn_mfma_f32_16x16x32_bf16(a0, b0, acc[0][0], 0, 0, 0);
            acc[0][1] = __builtin_amdgcn_mfma_f32_16x16x32_bf16(a0, b1, acc[0][1], 0, 0, 0);
            acc[1][0] = __builtin_amdgcn_mfma_f32_16x16x32_bf16(a1, b0, acc[1][0], 0, 0, 0);
            acc[1][1] = __builtin_amdgcn_mfma_f32_16x16x32_bf16(a1, b1, acc[1][1], 0, 0, 0);
        }
        G2_WRITE(cur ^ 1);
        __syncthreads();
        cur ^= 1;
    }
#undef G2_LOAD
#undef G2_WRITE

#pragma unroll
    for (int m = 0; m < 2; ++m)
#pragma unroll
        for (int n = 0; n < 2; ++n) {
            int col = h0 + wn * 32 + n * 16 + lr;
            int sbase = wm * 32 + m * 16 + lg * 4;
#pragma unroll
            for (int q = 0; q < 4; ++q) {
                int slot = sbase + q;
                int tok = toks[slot];
                if (tok >= 0)
                    atomicAdd(&out[(size_t)tok * H_DIM + col], acc[m][n][q] * wts[slot]);
            }
        }
}

extern "C" void kernel_launch(void* const* d_in, const int* in_sizes, int n_in,
                              void* d_out, int out_size, void* d_ws, size_t ws_size,
                              hipStream_t stream) {
    const float* hs   = (const float*)d_in[0];
    const float* gw   = (const float*)d_in[1];
    const float* bias = (const float*)d_in[2];
    const float* w13  = (const float*)d_in[3];
    const float* w2   = (const float*)d_in[4];
    float* out = (float*)d_out;

    char* ws = (char*)d_ws;
    int*   cnt      = (int*)(ws + 0);          // 64 B
    int*   tile_e   = (int*)(ws + 64);         // 320 B
    int*   tile_r0  = (int*)(ws + 384);        // 320 B (pad to 1024)
    int*   tok_list = (int*)(ws + 1024);       // 131072 -> 132096
    float* w_list   = (float*)(ws + 132096);   // 131072 -> 263168
    int*   A_tok    = (int*)(ws + 263168);     // 20480  -> 283648
    float* A_w      = (float*)(ws + 283648);   // 20480  -> 304128
    u16*   act      = (u16*)(ws + 304128);     // 5242880 -> 5547008
    u16*   hs_bf    = (u16*)(ws + 5547008);    // 8388608 -> ~13.3 MB

    hipMemsetAsync(d_out, 0, (size_t)T_TOK * H_DIM * sizeof(float), stream);
    hipMemsetAsync(cnt, 0, 64, stream);

    router_kernel<<<T_TOK / 4, 256, 0, stream>>>(hs, gw, bias, cnt, tok_list, w_list, hs_bf);
    scatter_build<<<(E_EXP * T_TOK) / 256, 256, 0, stream>>>(cnt, tok_list, w_list, A_tok, A_w, tile_e, tile_r0);

    gemm1_act<<<MAX_TILES * 8, 256, 0, stream>>>(hs_bf, w13, A_tok, tile_e, tile_r0, act);
    gemm2_scatter<<<MAX_TILES * 32, 256, 0, stream>>>(act, w2, A_tok, A_w, tile_e, tile_r0, out);
}